// Round 6
// baseline (63.351 us; speedup 1.0000x reference)
//
#include <hip/hip_runtime.h>
#include <math.h>

// Problem constants (fixed by setup_inputs)
constexpr int N    = 4;
constexpr int C    = 16;
constexpr int Hin  = 288;
constexpr int Win  = 1216;
constexpr int Hout = 800;
constexpr int Wout = 400;

// Base-grid constants: xs/ys are float32 arrays in the reference
// (explicit dtype). Python-f64 scalars are weak → cast to f32 first:
// xs[w] = f32( f32(-9.975) + f32( f32(0.05) * w ) ).
constexpr double grd = 0.05 * (800.0 / (double)Hout);        // 0.05 (f64)
constexpr float  GR  = (float)grd;                            // f32(0.05)
constexpr float  CX0 = (float)(-10.0 + grd / 2.0);            // f32(-9.975)
constexpr float  CY0 = (float)( 46.0 - grd / 2.0);            // f32(45.975)

// Register barrier: prevents the compiler from fusing a rounded multiply
// into a later add (keeps ops separately rounded exactly where numpy's
// ufuncs are separately rounded).
__device__ __forceinline__ float fbar(float x) {
    asm volatile("" : "+v"(x));
    return x;
}

__global__ __launch_bounds__(256) void bev_sample_kernel(
    const float* __restrict__ x,      // (N, C, Hin, Win)
    const float* __restrict__ theta,  // (N, 3, 3)
    const float* __restrict__ shift,  // (N,)
    float* __restrict__ out)          // (N, C, Hout, Wout)
{
    int idx = blockIdx.x * 256 + threadIdx.x;
    if (idx >= N * Hout * Wout) return;

    int w = idx % Wout;
    int t = idx / Wout;
    int h = t % Hout;
    int n = t / Hout;

    // f32 base grid, exact reference values.
    float bx = CX0 + fbar(GR * (float)w);
    float by = CY0 - fbar(GR * (float)h);

    const float* th = theta + n * 9;
    float t00 = th[0], t01 = th[1], t02 = th[2];
    float t10 = th[3], t11 = th[4], t12 = th[5];
    float t20 = th[6], t21 = th[7], t22 = th[8];

    // Einsum flavor F: ascending-k FMA accumulation, as produced by both
    // Eigen GEMM (jax-CPU dot_general) and numpy's SIMD muladd einsum path:
    //   acc = fma(bx,t0,0) = RN(bx*t0)
    //   acc = fma(by,t1,acc)              <- single-rounded FMA
    //   acc = fma(1.0,t2,acc) = RN(acc+t2) <- plain rounded add
    // At the projective singularity (g2~0) the texel decision amplifies a
    // 1-ulp g2 difference into ~0.1-1 texel; only the exact ref flavor of
    // g2 matches the harness reference there.
    float g0 = fbar(__builtin_fmaf(by, t01, fbar(bx * t00))) + t02;
    float g1 = fbar(__builtin_fmaf(by, t11, fbar(bx * t10))) + t12;
    float g2 = fbar(__builtin_fmaf(by, t21, fbar(bx * t20))) + t22;

    // Correctly-rounded IEEE f32 divisions (matches numpy ufunc divide).
    float p0 = g0 / g2;
    float p1 = g1 / g2;

    float gx = fbar(p0 / 608.0f) - 1.0f;
    float gy = fbar((p1 - shift[n]) / 144.0f) - 1.0f;

    // Unnormalize, separately rounded: ((g+1)*Win - 1)*0.5
    float ix = (fbar((gx + 1.0f) * (float)Win) - 1.0f) * 0.5f;
    float iy = (fbar((gy + 1.0f) * (float)Hin) - 1.0f) * 0.5f;

    float ix0f = floorf(ix);
    float iy0f = floorf(iy);
    float wx = ix - ix0f;
    float wy = iy - iy0f;

    int x0 = (int)fminf(fmaxf(ix0f,        0.0f), (float)(Win - 1));
    int x1 = (int)fminf(fmaxf(ix0f + 1.0f, 0.0f), (float)(Win - 1));
    int y0 = (int)fminf(fmaxf(iy0f,        0.0f), (float)(Hin - 1));
    int y1 = (int)fminf(fmaxf(iy0f + 1.0f, 0.0f), (float)(Hin - 1));

    float omwx = 1.0f - wx;
    float omwy = 1.0f - wy;

    int i00 = y0 * Win + x0;
    int i01 = y0 * Win + x1;
    int i10 = y1 * Win + x0;
    int i11 = y1 * Win + x1;

    const float* xb = x + (size_t)n * C * Hin * Win;
    size_t obase = ((size_t)(n * C) * Hout + h) * Wout + w;

    #pragma unroll
    for (int c = 0; c < C; ++c) {
        const float* p = xb + (size_t)c * Hin * Win;
        // numpy-order, separately-rounded interpolation:
        // ((v00*(1-wx))*(1-wy) + (v01*wx)*(1-wy)) + (v10*(1-wx))*wy + (v11*wx)*wy
        float r = fbar(fbar(p[i00] * omwx) * omwy)
                + fbar(fbar(p[i01] * wx)   * omwy);
        r = r + fbar(fbar(p[i10] * omwx) * wy);
        r = r + fbar(fbar(p[i11] * wx)   * wy);
        out[obase + (size_t)c * Hout * Wout] = r;
    }
}

extern "C" void kernel_launch(void* const* d_in, const int* in_sizes, int n_in,
                              void* d_out, int out_size, void* d_ws, size_t ws_size,
                              hipStream_t stream) {
    const float* x     = (const float*)d_in[0];
    const float* theta = (const float*)d_in[1];
    const float* shift = (const float*)d_in[2];
    float* out = (float*)d_out;

    int total = N * Hout * Wout;  // 1,280,000 pixel threads
    int blocks = (total + 255) / 256;
    bev_sample_kernel<<<blocks, 256, 0, stream>>>(x, theta, shift, out);
}

// Round 7
// 46.877 us; speedup vs baseline: 1.3514x; 1.3514x over previous
//
#include <hip/hip_runtime.h>
#include <math.h>

// Problem constants (fixed by setup_inputs)
constexpr int N    = 4;
constexpr int C    = 16;
constexpr int Hin  = 288;
constexpr int Win  = 1216;
constexpr int Hout = 800;
constexpr int Wout = 400;

// Base-grid constants: xs/ys are float32 arrays in the reference
// (explicit dtype). Python-f64 scalars are weak → cast to f32 first:
// xs[w] = f32( f32(-9.975) + f32( f32(0.05) * w ) ).
constexpr double grd = 0.05 * (800.0 / (double)Hout);        // 0.05 (f64)
constexpr float  GR  = (float)grd;                            // f32(0.05)
constexpr float  CX0 = (float)(-10.0 + grd / 2.0);            // f32(-9.975)
constexpr float  CY0 = (float)( 46.0 - grd / 2.0);            // f32(45.975)

// Register barrier: keeps ops separately rounded exactly where the numpy
// reference's ufuncs are separately rounded. ONLY used in the per-pixel
// coordinate chain (correctness-critical texel selection); the channel
// loop is barrier-free so the compiler can batch all 64 gathers.
__device__ __forceinline__ float fbar(float x) {
    asm volatile("" : "+v"(x));
    return x;
}

__global__ __launch_bounds__(256) void bev_sample_kernel(
    const float* __restrict__ x,      // (N, C, Hin, Win)
    const float* __restrict__ theta,  // (N, 3, 3)
    const float* __restrict__ shift,  // (N,)
    float* __restrict__ out)          // (N, C, Hout, Wout)
{
    int idx = blockIdx.x * 256 + threadIdx.x;
    if (idx >= N * Hout * Wout) return;

    int w = idx % Wout;
    int t = idx / Wout;
    int h = t % Hout;
    int n = t / Hout;

    // ---- coordinate chain: bit-exact vs harness np reference (round 6) ----
    float bx = CX0 + fbar(GR * (float)w);
    float by = CY0 - fbar(GR * (float)h);

    const float* th = theta + n * 9;
    float t00 = th[0], t01 = th[1], t02 = th[2];
    float t10 = th[3], t11 = th[4], t12 = th[5];
    float t20 = th[6], t21 = th[7], t22 = th[8];

    // Einsum flavor F: ascending-k FMA accumulation (matches the reference).
    float g0 = fbar(__builtin_fmaf(by, t01, fbar(bx * t00))) + t02;
    float g1 = fbar(__builtin_fmaf(by, t11, fbar(bx * t10))) + t12;
    float g2 = fbar(__builtin_fmaf(by, t21, fbar(bx * t20))) + t22;

    float p0 = g0 / g2;
    float p1 = g1 / g2;

    float gx = fbar(p0 / 608.0f) - 1.0f;
    float gy = fbar((p1 - shift[n]) / 144.0f) - 1.0f;

    float ix = (fbar((gx + 1.0f) * (float)Win) - 1.0f) * 0.5f;
    float iy = (fbar((gy + 1.0f) * (float)Hin) - 1.0f) * 0.5f;

    float ix0f = floorf(ix);
    float iy0f = floorf(iy);
    float wx = ix - ix0f;
    float wy = iy - iy0f;

    int x0 = (int)fminf(fmaxf(ix0f,        0.0f), (float)(Win - 1));
    int x1 = (int)fminf(fmaxf(ix0f + 1.0f, 0.0f), (float)(Win - 1));
    int y0 = (int)fminf(fmaxf(iy0f,        0.0f), (float)(Hin - 1));
    int y1 = (int)fminf(fmaxf(iy0f + 1.0f, 0.0f), (float)(Hin - 1));

    float omwx = 1.0f - wx;
    float omwy = 1.0f - wy;
    float w00 = omwx * omwy;
    float w01 = wx * omwy;
    float w10 = omwx * wy;
    float w11 = wx * wy;

    int i00 = y0 * Win + x0;
    int i01 = y0 * Win + x1;
    int i10 = y1 * Win + x0;
    int i11 = y1 * Win + x1;

    const float* xb = x + (size_t)n * C * Hin * Win;
    size_t obase = ((size_t)(n * C) * Hout + h) * Wout + w;

    // ---- phase 1: issue all 64 gathers (independent -> MLP=64) ----
    float v00[C], v01[C], v10[C], v11[C];
    #pragma unroll
    for (int c = 0; c < C; ++c) {
        const float* p = xb + (size_t)c * (Hin * Win);
        v00[c] = p[i00];
        v01[c] = p[i01];
        v10[c] = p[i10];
        v11[c] = p[i11];
    }

    // ---- phase 2: combine + streaming (nontemporal) stores ----
    // Output is write-once/never-read: bypass L2 so the 80 MB stream does
    // not evict the ~18 MB hot gather footprint.
    #pragma unroll
    for (int c = 0; c < C; ++c) {
        float r = v00[c] * w00 + v01[c] * w01 + v10[c] * w10 + v11[c] * w11;
        __builtin_nontemporal_store(r, &out[obase + (size_t)c * (Hout * Wout)]);
    }
}

extern "C" void kernel_launch(void* const* d_in, const int* in_sizes, int n_in,
                              void* d_out, int out_size, void* d_ws, size_t ws_size,
                              hipStream_t stream) {
    const float* x     = (const float*)d_in[0];
    const float* theta = (const float*)d_in[1];
    const float* shift = (const float*)d_in[2];
    float* out = (float*)d_out;

    int total = N * Hout * Wout;  // 1,280,000 pixel threads = 5000 blocks
    int blocks = (total + 255) / 256;
    bev_sample_kernel<<<blocks, 256, 0, stream>>>(x, theta, shift, out);
}